// Round 1
// baseline (151.298 us; speedup 1.0000x reference)
//
#include <hip/hip_runtime.h>

#define NROWS 4096
#define NCOLS 4096
#define TAU 0.95f
#define MARGIN 1.0f
#define INV_TAU (1.0f / TAU)
#define LN2F 0.69314718056f

// Kernel 1: one block per row. R3 change vs R2: thread->element mapping is now
// column-strided (thread t owns int4 groups t, t+256, t+512, t+768) so every
// global load instruction is lane-contiguous (16B/lane coalesced). The old
// mapping (16 contiguous elems/thread) made each wave-load touch 32 half-used
// 128B lines (64B lane stride) -> 4x line-transaction amplification in the
// TA/L1 path; counters showed neither HBM (19%) nor VALU (39%) saturated.
// Prefix sums for the 4 quarter-starts come from ONE packed 16-bit-field scan
// (two u32s), same shuffle/barrier count as before.
__global__ __launch_bounds__(256) void attncut_kernel(
    const float* __restrict__ cut_y, const int* __restrict__ cut_label,
    float* __restrict__ partials) {
  const int row = blockIdx.x;
  const int t = threadIdx.x;
  const int lane = t & 63;
  const int wid = t >> 6;

  const int4* lab4 = (const int4*)(cut_label + (size_t)row * NCOLS);
  const float4* yy4 = (const float4*)(cut_y + (size_t)row * NCOLS);

  // Fully coalesced: per instruction, lane l reads 16B at base + l*16B.
  const int4 L0 = lab4[t];
  const int4 L1 = lab4[t + 256];
  const int4 L2 = lab4[t + 512];
  const int4 L3 = lab4[t + 768];
  const float4 Y0 = yy4[t];
  const float4 Y1 = yy4[t + 256];
  const float4 Y2 = yy4[t + 512];
  const float4 Y3 = yy4[t + 768];

  // Per-quarter label sums for this thread's 4-element groups (each <= 4).
  const int s0 = L0.x + L0.y + L0.z + L0.w;
  const int s1 = L1.x + L1.y + L1.z + L1.w;
  const int s2 = L2.x + L2.y + L2.z + L2.w;
  const int s3 = L3.x + L3.y + L3.z + L3.w;

  // Pack 4 sums into 16-bit fields of two u32s; one scan covers all quarters.
  // Field max = 1024 (per-quarter total) << 65536: no cross-field carry.
  unsigned int pa = (unsigned int)s0 | ((unsigned int)s1 << 16);
  unsigned int pb = (unsigned int)s2 | ((unsigned int)s3 << 16);

  unsigned int xa = pa, xb = pb;  // wave-inclusive scan
#pragma unroll
  for (int off = 1; off < 64; off <<= 1) {
    unsigned int va = __shfl_up(xa, off, 64);
    unsigned int vb = __shfl_up(xb, off, 64);
    if (lane >= off) {
      xa += va;
      xb += vb;
    }
  }
  __shared__ unsigned int wsA[4], wsB[4];
  if (lane == 63) {
    wsA[wid] = xa;
    wsB[wid] = xb;
  }
  __syncthreads();
  unsigned int prevA = 0, prevB = 0;
#pragma unroll
  for (int w = 0; w < 4; ++w)
    if (w < wid) {
      prevA += wsA[w];
      prevB += wsB[w];
    }
  const unsigned int totA = wsA[0] + wsA[1] + wsA[2] + wsA[3];
  const unsigned int totB = wsB[0] + wsB[1] + wsB[2] + wsB[3];

  // Exclusive prefix (within quarter) for this thread, per 16-bit field.
  const unsigned int exA = prevA + xa - pa;
  const unsigned int exB = prevB + xb - pb;

  const int q0 = (int)(totA & 0xffffu), q1 = (int)(totA >> 16);
  const int q2 = (int)(totB & 0xffffu), q3 = (int)(totB >> 16);
  const float Tf = (float)(q0 + q1 + q2 + q3);

  // Global inclusive-count bases at each quarter-group start.
  int c0 = (int)(exA & 0xffffu);
  int c1 = q0 + (int)(exA >> 16);
  int c2 = q0 + q1 + (int)(exB & 0xffffu);
  int c3 = q0 + q1 + q2 + (int)(exB >> 16);

  float na = 0.f;  // sum exp(r/tau)
  float l2 = 0.f;  // sum log2(y) (grouped as log2 of 4-products)

  // Element index e = EBASE + j (j=1..4 via db+j), k = e, denom = k + T.
#define QSTEP(cv, LV, YV, EBASE)                                              \
  {                                                                           \
    const float db = (float)(EBASE) + Tf;                                     \
    cv += LV.x;                                                               \
    {                                                                         \
      float r = (cv > 0) ? __fdividef(2.0f * (float)cv, db + 1.0f) : 0.f;     \
      na += __expf(r * INV_TAU);                                              \
    }                                                                         \
    cv += LV.y;                                                               \
    {                                                                         \
      float r = (cv > 0) ? __fdividef(2.0f * (float)cv, db + 2.0f) : 0.f;     \
      na += __expf(r * INV_TAU);                                              \
    }                                                                         \
    cv += LV.z;                                                               \
    {                                                                         \
      float r = (cv > 0) ? __fdividef(2.0f * (float)cv, db + 3.0f) : 0.f;     \
      na += __expf(r * INV_TAU);                                              \
    }                                                                         \
    cv += LV.w;                                                               \
    {                                                                         \
      float r = (cv > 0) ? __fdividef(2.0f * (float)cv, db + 4.0f) : 0.f;     \
      na += __expf(r * INV_TAU);                                              \
    }                                                                         \
    /* y in (1e-4, 1): product of 4 in (1e-16, 1], safe f32; 1 v_log per 4 */ \
    l2 += __log2f(YV.x * YV.y * YV.z * YV.w);                                 \
  }

  QSTEP(c0, L0, Y0, 4 * t)
  QSTEP(c1, L1, Y1, 1024 + 4 * t)
  QSTEP(c2, L2, Y2, 2048 + 4 * t)
  QSTEP(c3, L3, Y3, 3072 + 4 * t)
#undef QSTEP

  // Block reduction of (na, l2).
#pragma unroll
  for (int off = 32; off > 0; off >>= 1) {
    na += __shfl_down(na, off, 64);
    l2 += __shfl_down(l2, off, 64);
  }
  __shared__ float nred[4], lred[4];
  if (lane == 0) {
    nred[wid] = na;
    lred[wid] = l2;
  }
  __syncthreads();
  if (t == 0) {
    const float norm = nred[0] + nred[1] + nred[2] + nred[3];
    const float lnsum = (lred[0] + lred[1] + lred[2] + lred[3]) * LN2F;
    partials[row] = -lnsum / (norm * (float)NROWS);  // distinct addr per block
  }
}

// Kernel 2 (single block): sum the 4096 per-row partials + rerank hinge loss.
__global__ __launch_bounds__(256) void finish_kernel(
    const float* __restrict__ partials, const float* __restrict__ rerank_y,
    float* __restrict__ out) {
  const int t = threadIdx.x;
  const int lane = t & 63, wid = t >> 6;

  float acc = 0.f;
  const float4* p4 = (const float4*)partials;  // 4096 floats = 1024 float4
#pragma unroll
  for (int i = 0; i < 4; ++i) {
    float4 v = p4[t + 256 * i];
    acc += (v.x + v.y) + (v.z + v.w);
  }

  float racc = 0.f;
  const float4* y4 = (const float4*)rerank_y;  // 8192 floats; float4 = 2 pairs
#pragma unroll
  for (int i = 0; i < 8; ++i) {
    float4 v = y4[t + 256 * i];
    racc += fmaxf(0.f, MARGIN - (v.x - v.y));
    racc += fmaxf(0.f, MARGIN - (v.z - v.w));
  }
  acc += racc * (1.0f / 4096.0f);

#pragma unroll
  for (int off = 32; off > 0; off >>= 1) acc += __shfl_down(acc, off, 64);
  __shared__ float ws[4];
  if (lane == 0) ws[wid] = acc;
  __syncthreads();
  if (t == 0) out[0] = (ws[0] + ws[1]) + (ws[2] + ws[3]);
}

extern "C" void kernel_launch(void* const* d_in, const int* in_sizes, int n_in,
                              void* d_out, int out_size, void* d_ws, size_t ws_size,
                              hipStream_t stream) {
  const float* rerank_y = (const float*)d_in[0];   // (8192, 1) f32
  const float* cut_y = (const float*)d_in[1];      // (4096, 4096, 1) f32
  // d_in[2] = rerank_label, unused by the reference loss
  const int* cut_label = (const int*)d_in[3];      // (4096, 4096) i32
  float* out = (float*)d_out;                      // scalar f32
  float* partials = (float*)d_ws;                  // 4096 f32 (16 KB scratch)

  attncut_kernel<<<NROWS, 256, 0, stream>>>(cut_y, cut_label, partials);
  finish_kernel<<<1, 256, 0, stream>>>(partials, rerank_y, out);
}